// Round 1
// baseline (402.188 us; speedup 1.0000x reference)
//
#include <hip/hip_runtime.h>

typedef __bf16 bf16_t;
typedef bf16_t bf16x8 __attribute__((ext_vector_type(8)));
typedef float floatx4 __attribute__((ext_vector_type(4)));
typedef unsigned short ushort_t;

#define HLD 264   // h_lds row stride in bf16 elems (256 + 8 pad -> even bank spread)
#define OLD 68    // out_s / wfcc_s row stride in f32 (64 + 4 pad)

__device__ __forceinline__ floatx4 mfma16(bf16x8 a, bf16x8 b, floatx4 c) {
  return __builtin_amdgcn_mfma_f32_16x16x32_bf16(a, b, c, 0, 0, 0);
}

__device__ __forceinline__ float tanh_fast(float x) {
  x = fminf(15.0f, fmaxf(-15.0f, x));      // avoid inf/inf NaN
  float e = __expf(-2.0f * x);
  return (1.0f - e) / (1.0f + e);
}

__device__ __forceinline__ bf16x8 cvt8(floatx4 f0, floatx4 f1) {
  bf16x8 r;
  r[0] = (bf16_t)f0[0]; r[1] = (bf16_t)f0[1]; r[2] = (bf16_t)f0[2]; r[3] = (bf16_t)f0[3];
  r[4] = (bf16_t)f1[0]; r[5] = (bf16_t)f1[1]; r[6] = (bf16_t)f1[2]; r[7] = (bf16_t)f1[3];
  return r;
}

// Pack weights (row-major [N][K] f32) into bf16 MFMA B-fragment order:
// frag (ntile, kstep): lane holds B[k = kstep*32 + (lane>>4)*8 + j][n = ntile*16 + (lane&15)]
//                    = W[n][k...k+7]  (contiguous in W's row -> coalesced-ish reads)
__global__ void pack_all(const float* __restrict__ Wh2h, const float* __restrict__ Wi2h,
                         const float* __restrict__ Wh2o, ushort_t* __restrict__ ws) {
  int id = blockIdx.x * 256 + threadIdx.x;
  const float* W; int ldk, ksteps; ushort_t* dst; int rel;
  if (id < 8192)       { W = Wh2h; ldk = 256; ksteps = 8; dst = ws;         rel = id; }          // 16 ntiles x 8 ksteps
  else if (id < 10240) { W = Wi2h; ldk = 64;  ksteps = 2; dst = ws + 65536; rel = id - 8192; }   // 16 x 2
  else if (id < 12288) { W = Wh2o; ldk = 256; ksteps = 8; dst = ws + 81920; rel = id - 10240; }  // 4 x 8
  else return;
  int lane = rel & 63, fi = rel >> 6;
  int kstep = fi % ksteps, ntile = fi / ksteps;
  int n  = ntile * 16 + (lane & 15);
  int k0 = kstep * 32 + ((lane >> 4) << 3);
  const float* src = W + (size_t)n * ldk + k0;
  floatx4 f0 = *(const floatx4*)src;
  floatx4 f1 = *(const floatx4*)(src + 4);
  ((bf16x8*)dst)[rel] = cvt8(f0, f1);
}

// Fused RNN: 256 blocks x 512 threads; block owns 32 batch rows for all 16 steps.
__global__ __launch_bounds__(512, 2)
void rnn_fused(const float* __restrict__ x,      // [16][8192][64]
               const float* __restrict__ hc1,    // [8192][256]
               const float* __restrict__ hc2,
               const float* __restrict__ hc3,
               const float* __restrict__ hc4,
               const float* __restrict__ b_i2h,  // [256]
               const float* __restrict__ b_h2h,  // [256]
               const float* __restrict__ b_h2o,  // [64]
               const float* __restrict__ W_fcc,  // [8][64]
               const float* __restrict__ b_fcc,  // [8]
               const ushort_t* __restrict__ wsW,
               float* __restrict__ out_seq,      // [16][8192][8]
               float* __restrict__ hc1_f,        // [8192][256]
               float* __restrict__ hc2_o,
               float* __restrict__ hc3_o,
               float* __restrict__ hc4_o,
               float* __restrict__ i2h_seq,      // [16][8192][256]
               float* __restrict__ h2h_seq) {    // [16][8192][256]
  __shared__ bf16_t h_lds[32 * HLD];
  __shared__ float  out_s[32 * OLD];
  __shared__ float  wfcc_s[8 * OLD];

  const int tid  = threadIdx.x;
  const int lane = tid & 63;
  const int wv   = tid >> 6;        // wave 0..7
  const int q    = lane >> 4;       // quad 0..3
  const int c    = lane & 15;
  const int r0   = blockIdx.x * 32; // batch row base

  const bf16x8* WH = (const bf16x8*)(wsW);          // [16 ntiles][8 ksteps][64 lanes]
  const bf16x8* WI = (const bf16x8*)(wsW + 65536);  // [16][2][64]
  const bf16x8* WO = (const bf16x8*)(wsW + 81920);  // [4][8][64]

  // pass-through hc2..4 copies, overlapped with the store-bound main loop
  {
    const floatx4* s2 = (const floatx4*)(hc2 + (size_t)r0 * 256);
    const floatx4* s3 = (const floatx4*)(hc3 + (size_t)r0 * 256);
    const floatx4* s4 = (const floatx4*)(hc4 + (size_t)r0 * 256);
    floatx4* d2 = (floatx4*)(hc2_o + (size_t)r0 * 256);
    floatx4* d3 = (floatx4*)(hc3_o + (size_t)r0 * 256);
    floatx4* d4 = (floatx4*)(hc4_o + (size_t)r0 * 256);
    for (int i = tid; i < 2048; i += 512) { d2[i] = s2[i]; d3[i] = s3[i]; d4[i] = s4[i]; }
  }

  // stage h0 (bf16) into LDS
  for (int i = tid; i < 2048; i += 512) {
    int m = i >> 6, k4 = (i & 63) * 4;
    floatx4 v = *(const floatx4*)&hc1[(size_t)(r0 + m) * 256 + k4];
    h_lds[m * HLD + k4 + 0] = (bf16_t)v[0];
    h_lds[m * HLD + k4 + 1] = (bf16_t)v[1];
    h_lds[m * HLD + k4 + 2] = (bf16_t)v[2];
    h_lds[m * HLD + k4 + 3] = (bf16_t)v[3];
  }
  // stage W_fcc (padded stride: no 8-way bank conflict in fcc)
  {
    int o = tid >> 6, i = tid & 63;
    if (tid < 512) wfcc_s[o * OLD + i] = W_fcc[tid];
  }

  // per-wave constants: phase A covers ntiles n0, n0+1 of 16
  const int n0 = wv * 2;
  const float bI0 = b_i2h[n0 * 16 + c], bI1 = b_i2h[(n0 + 1) * 16 + c];
  const float bH0 = b_h2h[n0 * 16 + c], bH1 = b_h2h[(n0 + 1) * 16 + c];
  const int mo = wv >> 2, no = wv & 3;  // phase B: wave -> (mtile, ntile of 4)
  const float bO = b_h2o[no * 16 + c];
  const int fm = tid >> 3, fo = tid & 7;
  const float bF = b_fcc[fo];

  // hoist loop-invariant weight fragments into registers (~112 VGPRs)
  bf16x8 wh[8][2], wi[2][2], wo[8];
#pragma unroll
  for (int k = 0; k < 8; ++k) {
    wh[k][0] = WH[((n0)     * 8 + k) * 64 + lane];
    wh[k][1] = WH[((n0 + 1) * 8 + k) * 64 + lane];
    wo[k]    = WO[(no * 8 + k) * 64 + lane];
  }
#pragma unroll
  for (int k = 0; k < 2; ++k) {
    wi[k][0] = WI[((n0)     * 2 + k) * 64 + lane];
    wi[k][1] = WI[((n0 + 1) * 2 + k) * 64 + lane];
  }

  __syncthreads();

  for (int t = 0; t < 16; ++t) {
    // ---------- Phase A: h2h (K=256) + i2h (K=64), this wave's 2 ntiles x 2 mtiles ----------
    floatx4 accH[2][2], accI[2][2];
#pragma unroll
    for (int a = 0; a < 2; ++a)
#pragma unroll
      for (int b = 0; b < 2; ++b) { accH[a][b] = (floatx4){0,0,0,0}; accI[a][b] = (floatx4){0,0,0,0}; }

#pragma unroll
    for (int k = 0; k < 8; ++k) {
      bf16x8 a0 = *(const bf16x8*)&h_lds[(c)      * HLD + k * 32 + q * 8];
      bf16x8 a1 = *(const bf16x8*)&h_lds[(16 + c) * HLD + k * 32 + q * 8];
      accH[0][0] = mfma16(a0, wh[k][0], accH[0][0]);
      accH[1][0] = mfma16(a1, wh[k][0], accH[1][0]);
      accH[0][1] = mfma16(a0, wh[k][1], accH[0][1]);
      accH[1][1] = mfma16(a1, wh[k][1], accH[1][1]);
    }
    const float* xt = x + ((size_t)t * 8192 + r0) * 64;
#pragma unroll
    for (int k = 0; k < 2; ++k) {
      const float* p0 = xt + (c)      * 64 + k * 32 + q * 8;
      const float* p1 = xt + (16 + c) * 64 + k * 32 + q * 8;
      bf16x8 a0 = cvt8(*(const floatx4*)p0, *(const floatx4*)(p0 + 4));
      bf16x8 a1 = cvt8(*(const floatx4*)p1, *(const floatx4*)(p1 + 4));
      accI[0][0] = mfma16(a0, wi[k][0], accI[0][0]);
      accI[1][0] = mfma16(a1, wi[k][0], accI[1][0]);
      accI[0][1] = mfma16(a0, wi[k][1], accI[0][1]);
      accI[1][1] = mfma16(a1, wi[k][1], accI[1][1]);
    }

    // epilogue: store i2h_seq/h2h_seq, compute h_new = tanh(i2h + h2h)
    float hnew[2][2][4];
    const size_t bt = (size_t)t * 8192 + r0;
#pragma unroll
    for (int mt = 0; mt < 2; ++mt) {
#pragma unroll
      for (int nl = 0; nl < 2; ++nl) {
        const float bIv = nl ? bI1 : bI0;
        const float bHv = nl ? bH1 : bH0;
#pragma unroll
        for (int rg = 0; rg < 4; ++rg) {
          int row = mt * 16 + q * 4 + rg;     // C/D: row = quad*4 + reg
          int col = (n0 + nl) * 16 + c;       //      col = lane & 15
          size_t gi = (bt + row) * 256 + col;
          float vi = accI[mt][nl][rg] + bIv;
          float vh = accH[mt][nl][rg] + bHv;
          i2h_seq[gi] = vi;
          h2h_seq[gi] = vh;
          float hv = tanh_fast(vi + vh);
          hnew[mt][nl][rg] = hv;
          if (t == 15) hc1_f[(size_t)(r0 + row) * 256 + col] = hv;
        }
      }
    }
    __syncthreads();   // all waves done reading old h
#pragma unroll
    for (int mt = 0; mt < 2; ++mt)
#pragma unroll
      for (int nl = 0; nl < 2; ++nl)
#pragma unroll
        for (int rg = 0; rg < 4; ++rg)
          h_lds[(mt * 16 + q * 4 + rg) * HLD + (n0 + nl) * 16 + c] = (bf16_t)hnew[mt][nl][rg];
    __syncthreads();   // h_new visible

    // ---------- Phase B: h2o (wave -> 1 of 2 mtiles x 1 of 4 ntiles), K=256 ----------
    floatx4 accO = (floatx4){0,0,0,0};
#pragma unroll
    for (int k = 0; k < 8; ++k) {
      bf16x8 a = *(const bf16x8*)&h_lds[(mo * 16 + c) * HLD + k * 32 + q * 8];
      accO = mfma16(a, wo[k], accO);
    }
#pragma unroll
    for (int rg = 0; rg < 4; ++rg)
      out_s[(mo * 16 + q * 4 + rg) * OLD + no * 16 + c] = tanh_fast(accO[rg] + bO);
    __syncthreads();   // out_s ready

    // ---------- fcc: 32 rows x 8 outputs, one thread each ----------
    if (tid < 256) {
      float s = bF;
#pragma unroll
      for (int i4 = 0; i4 < 16; ++i4) {
        floatx4 a = *(const floatx4*)&out_s[fm * OLD + i4 * 4];
        floatx4 w = *(const floatx4*)&wfcc_s[fo * OLD + i4 * 4];
        s += a[0]*w[0] + a[1]*w[1] + a[2]*w[2] + a[3]*w[3];
      }
      out_seq[(bt + fm) * 8 + fo] = s;
    }
    // no barrier needed here: next step's h_lds/out_s writes are fenced by the
    // barriers above (all waves must re-arrive before any overwrite)
  }
}

extern "C" void kernel_launch(void* const* d_in, const int* in_sizes, int n_in,
                              void* d_out, int out_size, void* d_ws, size_t ws_size,
                              hipStream_t stream) {
  (void)in_sizes; (void)n_in; (void)out_size; (void)ws_size;
  const float* x     = (const float*)d_in[0];
  // d_in[1] = cue (unused by the reference)
  const float* hc1   = (const float*)d_in[2];
  const float* hc2   = (const float*)d_in[3];
  const float* hc3   = (const float*)d_in[4];
  const float* hc4   = (const float*)d_in[5];
  const float* W_i2h = (const float*)d_in[6];
  const float* b_i2h = (const float*)d_in[7];
  const float* W_h2h = (const float*)d_in[8];
  const float* b_h2h = (const float*)d_in[9];
  const float* W_h2o = (const float*)d_in[10];
  const float* b_h2o = (const float*)d_in[11];
  const float* W_fcc = (const float*)d_in[12];
  const float* b_fcc = (const float*)d_in[13];

  float* out     = (float*)d_out;
  float* out_seq = out;                   // [16,8192,8]    1048576
  float* hc1_f   = out + 1048576;         // [8192,256]     2097152
  float* hc2_o   = out + 3145728;
  float* hc3_o   = out + 5242880;
  float* hc4_o   = out + 7340032;
  float* i2h_seq = out + 9437184;         // [16,8192,256]  33554432
  float* h2h_seq = out + 42991616;        // [16,8192,256]  33554432

  ushort_t* ws = (ushort_t*)d_ws;         // 196608 B of packed bf16 fragments

  pack_all<<<48, 256, 0, stream>>>(W_h2h, W_i2h, W_h2o, ws);
  rnn_fused<<<256, 512, 0, stream>>>(x, hc1, hc2, hc3, hc4,
                                     b_i2h, b_h2h, b_h2o, W_fcc, b_fcc,
                                     (const ushort_t*)ws,
                                     out_seq, hc1_f, hc2_o, hc3_o, hc4_o,
                                     i2h_seq, h2h_seq);
}

// Round 2
// 401.959 us; speedup vs baseline: 1.0006x; 1.0006x over previous
//
#include <hip/hip_runtime.h>

typedef __bf16 bf16_t;
typedef bf16_t bf16x8 __attribute__((ext_vector_type(8)));
typedef float floatx4 __attribute__((ext_vector_type(4)));
typedef unsigned short ushort_t;

#define HLD 264   // h_lds row stride in bf16 elems (256 + 8 pad)
#define OLD 68    // out_s / wfcc_s row stride in f32 (64 + 4 pad)

__device__ __forceinline__ floatx4 mfma16(bf16x8 a, bf16x8 b, floatx4 c) {
  return __builtin_amdgcn_mfma_f32_16x16x32_bf16(a, b, c, 0, 0, 0);
}

__device__ __forceinline__ float tanh_fast(float x) {
  x = fminf(15.0f, fmaxf(-15.0f, x));
  float e = __expf(-2.0f * x);
  return (1.0f - e) / (1.0f + e);
}

__device__ __forceinline__ bf16x8 cvt8(floatx4 f0, floatx4 f1) {
  bf16x8 r;
  r[0] = (bf16_t)f0[0]; r[1] = (bf16_t)f0[1]; r[2] = (bf16_t)f0[2]; r[3] = (bf16_t)f0[3];
  r[4] = (bf16_t)f1[0]; r[5] = (bf16_t)f1[1]; r[6] = (bf16_t)f1[2]; r[7] = (bf16_t)f1[3];
  return r;
}

// Pack weights (row-major [N][K] f32) into bf16 MFMA B-fragment order:
// frag (ntile, kstep): lane holds B[k = kstep*32 + (lane>>4)*8 + j][n = ntile*16 + (lane&15)]
__global__ void pack_all(const float* __restrict__ Wh2h, const float* __restrict__ Wi2h,
                         const float* __restrict__ Wh2o, ushort_t* __restrict__ ws) {
  int id = blockIdx.x * 256 + threadIdx.x;
  const float* W; int ldk, ksteps; ushort_t* dst; int rel;
  if (id < 8192)       { W = Wh2h; ldk = 256; ksteps = 8; dst = ws;         rel = id; }
  else if (id < 10240) { W = Wi2h; ldk = 64;  ksteps = 2; dst = ws + 65536; rel = id - 8192; }
  else if (id < 12288) { W = Wh2o; ldk = 256; ksteps = 8; dst = ws + 81920; rel = id - 10240; }
  else return;
  int lane = rel & 63, fi = rel >> 6;
  int kstep = fi % ksteps, ntile = fi / ksteps;
  int n  = ntile * 16 + (lane & 15);
  int k0 = kstep * 32 + ((lane >> 4) << 3);
  const float* src = W + (size_t)n * ldk + k0;
  floatx4 f0 = *(const floatx4*)src;
  floatx4 f1 = *(const floatx4*)(src + 4);
  ((bf16x8*)dst)[rel] = cvt8(f0, f1);
}

// Fused RNN: 256 blocks x 512 threads; block owns 32 batch rows, all 16 steps.
// ONE barrier per step; all global stores issued post-barrier so their drain
// overlaps the next step's compute (vmcnt(0)-before-s_barrier then waits on
// stores that have had a full step to retire).
__global__ __launch_bounds__(512, 2)
void rnn_fused(const float* __restrict__ x,      // [16][8192][64]
               const float* __restrict__ hc1,    // [8192][256]
               const float* __restrict__ hc2,
               const float* __restrict__ hc3,
               const float* __restrict__ hc4,
               const float* __restrict__ b_i2h,
               const float* __restrict__ b_h2h,
               const float* __restrict__ b_h2o,
               const float* __restrict__ W_fcc,  // [8][64]
               const float* __restrict__ b_fcc,
               const ushort_t* __restrict__ wsW,
               float* __restrict__ out_seq,      // [16][8192][8]
               float* __restrict__ hc1_f,        // [8192][256]
               float* __restrict__ hc2_o,
               float* __restrict__ hc3_o,
               float* __restrict__ hc4_o,
               float* __restrict__ i2h_seq,      // [16][8192][256]
               float* __restrict__ h2h_seq) {    // [16][8192][256]
  __shared__ bf16_t h_lds[2][32 * HLD];  // double-buffered hidden state
  __shared__ float  out_s[2][32 * OLD];  // double-buffered h2o output (fcc pipelined)
  __shared__ float  wfcc_s[8 * OLD];

  const int tid  = threadIdx.x;
  const int lane = tid & 63;
  const int wv   = tid >> 6;
  const int q    = lane >> 4;
  const int c    = lane & 15;
  const int r0   = blockIdx.x * 32;

  const bf16x8* WH = (const bf16x8*)(wsW);          // [16][8][64]
  const bf16x8* WI = (const bf16x8*)(wsW + 65536);  // [16][2][64]
  const bf16x8* WO = (const bf16x8*)(wsW + 81920);  // [4][8][64]

  // stage h0 (bf16) into h_lds[0]
  for (int i = tid; i < 2048; i += 512) {
    int m = i >> 6, k4 = (i & 63) * 4;
    floatx4 v = *(const floatx4*)&hc1[(size_t)(r0 + m) * 256 + k4];
    h_lds[0][m * HLD + k4 + 0] = (bf16_t)v[0];
    h_lds[0][m * HLD + k4 + 1] = (bf16_t)v[1];
    h_lds[0][m * HLD + k4 + 2] = (bf16_t)v[2];
    h_lds[0][m * HLD + k4 + 3] = (bf16_t)v[3];
  }
  { int o = tid >> 6, i = tid & 63; if (tid < 512) wfcc_s[o * OLD + i] = W_fcc[tid]; }

  const int n0 = wv * 2;
  const float bI0 = b_i2h[n0 * 16 + c], bI1 = b_i2h[(n0 + 1) * 16 + c];
  const float bH0 = b_h2h[n0 * 16 + c], bH1 = b_h2h[(n0 + 1) * 16 + c];
  const int mo = wv >> 2, no = wv & 3;
  const float bO = b_h2o[no * 16 + c];
  const int fm = tid >> 3, fo = tid & 7;
  const float bF = b_fcc[fo];

  // loop-invariant weight fragments in registers
  bf16x8 wh[8][2], wi[2][2], wo[8];
#pragma unroll
  for (int k = 0; k < 8; ++k) {
    wh[k][0] = WH[((n0)     * 8 + k) * 64 + lane];
    wh[k][1] = WH[((n0 + 1) * 8 + k) * 64 + lane];
    wo[k]    = WO[(no * 8 + k) * 64 + lane];
  }
#pragma unroll
  for (int k = 0; k < 2; ++k) {
    wi[k][0] = WI[((n0)     * 2 + k) * 64 + lane];
    wi[k][1] = WI[((n0 + 1) * 2 + k) * 64 + lane];
  }

  __syncthreads();

  for (int t = 0; t < 16; ++t) {
    const int p = t & 1;
    const size_t bt = (size_t)t * 8192 + r0;

    // ---- phase A: issue x loads first (latency hidden under h2h MFMA chain) ----
    const float* xt = x + bt * 64;
    floatx4 xv[2][4];
#pragma unroll
    for (int k = 0; k < 2; ++k) {
      const float* p0 = xt + (c)      * 64 + k * 32 + q * 8;
      const float* p1 = xt + (16 + c) * 64 + k * 32 + q * 8;
      xv[k][0] = *(const floatx4*)p0;  xv[k][1] = *(const floatx4*)(p0 + 4);
      xv[k][2] = *(const floatx4*)p1;  xv[k][3] = *(const floatx4*)(p1 + 4);
    }

    floatx4 accH[2][2], accI[2][2];
#pragma unroll
    for (int a = 0; a < 2; ++a)
#pragma unroll
      for (int b = 0; b < 2; ++b) { accH[a][b] = (floatx4){0,0,0,0}; accI[a][b] = (floatx4){0,0,0,0}; }

#pragma unroll
    for (int k = 0; k < 8; ++k) {
      bf16x8 a0 = *(const bf16x8*)&h_lds[p][(c)      * HLD + k * 32 + q * 8];
      bf16x8 a1 = *(const bf16x8*)&h_lds[p][(16 + c) * HLD + k * 32 + q * 8];
      accH[0][0] = mfma16(a0, wh[k][0], accH[0][0]);
      accH[1][0] = mfma16(a1, wh[k][0], accH[1][0]);
      accH[0][1] = mfma16(a0, wh[k][1], accH[0][1]);
      accH[1][1] = mfma16(a1, wh[k][1], accH[1][1]);
    }
#pragma unroll
    for (int k = 0; k < 2; ++k) {
      bf16x8 a0 = cvt8(xv[k][0], xv[k][1]);
      bf16x8 a1 = cvt8(xv[k][2], xv[k][3]);
      accI[0][0] = mfma16(a0, wi[k][0], accI[0][0]);
      accI[1][0] = mfma16(a1, wi[k][0], accI[1][0]);
      accI[0][1] = mfma16(a0, wi[k][1], accI[0][1]);
      accI[1][1] = mfma16(a1, wi[k][1], accI[1][1]);
    }

    // add biases in place (accI=vi, accH=vh stay live across the barrier),
    // write h_new bf16 into the other LDS buffer
#pragma unroll
    for (int mt = 0; mt < 2; ++mt)
#pragma unroll
      for (int nl = 0; nl < 2; ++nl) {
        const float bIv = nl ? bI1 : bI0;
        const float bHv = nl ? bH1 : bH0;
#pragma unroll
        for (int rg = 0; rg < 4; ++rg) {
          accI[mt][nl][rg] += bIv;
          accH[mt][nl][rg] += bHv;
          float hv = tanh_fast(accI[mt][nl][rg] + accH[mt][nl][rg]);
          h_lds[1 - p][(mt * 16 + q * 4 + rg) * HLD + (n0 + nl) * 16 + c] = (bf16_t)hv;
        }
      }

    __syncthreads();   // THE single barrier for step t

    // ---- post-barrier: all global stores (drain overlaps next step) ----
#pragma unroll
    for (int mt = 0; mt < 2; ++mt)
#pragma unroll
      for (int nl = 0; nl < 2; ++nl)
#pragma unroll
        for (int rg = 0; rg < 4; ++rg) {
          int row = mt * 16 + q * 4 + rg;
          int col = (n0 + nl) * 16 + c;
          size_t gi = (bt + row) * 256 + col;
          __builtin_nontemporal_store(accI[mt][nl][rg], &i2h_seq[gi]);
          __builtin_nontemporal_store(accH[mt][nl][rg], &h2h_seq[gi]);
          if (t == 15)
            hc1_f[(size_t)(r0 + row) * 256 + col] =
                tanh_fast(accI[mt][nl][rg] + accH[mt][nl][rg]);
        }

    // hc2..4 pass-through, 1/16th per step
    if (tid < 384) {
      int tensor = tid >> 7, j = (tid & 127) + t * 128;
      const float* s = tensor == 0 ? hc2 : (tensor == 1 ? hc3 : hc4);
      float*       d = tensor == 0 ? hc2_o : (tensor == 1 ? hc3_o : hc4_o);
      ((floatx4*)(d + (size_t)r0 * 256))[j] = ((const floatx4*)(s + (size_t)r0 * 256))[j];
    }

    // fcc for step t-1 (out_s[1-p] written in phase B(t-1), fenced by this barrier)
    if (t > 0 && tid < 256) {
      float s = bF;
#pragma unroll
      for (int i4 = 0; i4 < 16; ++i4) {
        floatx4 a = *(const floatx4*)&out_s[1 - p][fm * OLD + i4 * 4];
        floatx4 w = *(const floatx4*)&wfcc_s[fo * OLD + i4 * 4];
        s += a[0]*w[0] + a[1]*w[1] + a[2]*w[2] + a[3]*w[3];
      }
      out_seq[((size_t)(t - 1) * 8192 + r0 + fm) * 8 + fo] = s;
    }

    // ---- phase B: h2o on h_new (h_lds[1-p], fenced by this step's barrier) ----
    floatx4 accO = (floatx4){0,0,0,0};
#pragma unroll
    for (int k = 0; k < 8; ++k) {
      bf16x8 a = *(const bf16x8*)&h_lds[1 - p][(mo * 16 + c) * HLD + k * 32 + q * 8];
      accO = mfma16(a, wo[k], accO);
    }
#pragma unroll
    for (int rg = 0; rg < 4; ++rg)
      out_s[p][(mo * 16 + q * 4 + rg) * OLD + no * 16 + c] = tanh_fast(accO[rg] + bO);
  }

  __syncthreads();
  // fcc for step 15 (out_s[1])
  if (tid < 256) {
    float s = bF;
#pragma unroll
    for (int i4 = 0; i4 < 16; ++i4) {
      floatx4 a = *(const floatx4*)&out_s[1][fm * OLD + i4 * 4];
      floatx4 w = *(const floatx4*)&wfcc_s[fo * OLD + i4 * 4];
      s += a[0]*w[0] + a[1]*w[1] + a[2]*w[2] + a[3]*w[3];
    }
    out_seq[((size_t)15 * 8192 + r0 + fm) * 8 + fo] = s;
  }
}

extern "C" void kernel_launch(void* const* d_in, const int* in_sizes, int n_in,
                              void* d_out, int out_size, void* d_ws, size_t ws_size,
                              hipStream_t stream) {
  (void)in_sizes; (void)n_in; (void)out_size; (void)ws_size;
  const float* x     = (const float*)d_in[0];
  const float* hc1   = (const float*)d_in[2];
  const float* hc2   = (const float*)d_in[3];
  const float* hc3   = (const float*)d_in[4];
  const float* hc4   = (const float*)d_in[5];
  const float* W_i2h = (const float*)d_in[6];
  const float* b_i2h = (const float*)d_in[7];
  const float* W_h2h = (const float*)d_in[8];
  const float* b_h2h = (const float*)d_in[9];
  const float* W_h2o = (const float*)d_in[10];
  const float* b_h2o = (const float*)d_in[11];
  const float* W_fcc = (const float*)d_in[12];
  const float* b_fcc = (const float*)d_in[13];

  float* out     = (float*)d_out;
  float* out_seq = out;                   // [16,8192,8]
  float* hc1_f   = out + 1048576;         // [8192,256]
  float* hc2_o   = out + 3145728;
  float* hc3_o   = out + 5242880;
  float* hc4_o   = out + 7340032;
  float* i2h_seq = out + 9437184;         // [16,8192,256]
  float* h2h_seq = out + 42991616;        // [16,8192,256]

  ushort_t* ws = (ushort_t*)d_ws;

  pack_all<<<48, 256, 0, stream>>>(W_h2h, W_i2h, W_h2o, ws);
  rnn_fused<<<256, 512, 0, stream>>>(x, hc1, hc2, hc3, hc4,
                                     b_i2h, b_h2h, b_h2o, W_fcc, b_fcc,
                                     (const ushort_t*)ws,
                                     out_seq, hc1_f, hc2_o, hc3_o, hc4_o,
                                     i2h_seq, h2h_seq);
}